// Round 2
// baseline (458.472 us; speedup 1.0000x reference)
//
#include <hip/hip_runtime.h>
#include <hip/hip_bf16.h>

namespace {

constexpr int T = 4096, N = 256, U = 128, K = 32, P = 128;
constexpr int NK = N * K;           // 8192 scan lanes
constexpr int CL = 64;              // chunk length
constexpr int NCH = T / CL;         // 64 chunks total

typedef __attribute__((ext_vector_type(8))) short short8;   // 8 bf16
typedef __attribute__((ext_vector_type(4))) float f32x4;

__device__ __forceinline__ unsigned short f2bf(float f) {
  union { float f; unsigned u; } v; v.f = f;
  unsigned r = v.u + 0x7FFFu + ((v.u >> 16) & 1u);   // RNE
  return (unsigned short)(r >> 16);
}
__device__ __forceinline__ float bf2f(unsigned short s) {
  union { unsigned u; float f; } v; v.u = ((unsigned)s) << 16;
  return v.f;
}
__device__ __forceinline__ short8 ld8(const unsigned short* p) {
  return *reinterpret_cast<const short8*>(p);
}
// 8 packed (re|im) dwords -> separate re/im bf16x8 fragments
__device__ __forceinline__ void unpack8(const unsigned* p, short8& re, short8& im) {
  uint4 a = *reinterpret_cast<const uint4*>(p);
  uint4 b = *reinterpret_cast<const uint4*>(p + 4);
  union { short8 v; unsigned u[4]; } r, i;
  r.u[0] = (a.x & 0xFFFFu) | (a.y << 16);
  i.u[0] = (a.x >> 16)     | (a.y & 0xFFFF0000u);
  r.u[1] = (a.z & 0xFFFFu) | (a.w << 16);
  i.u[1] = (a.z >> 16)     | (a.w & 0xFFFF0000u);
  r.u[2] = (b.x & 0xFFFFu) | (b.y << 16);
  i.u[2] = (b.x >> 16)     | (b.y & 0xFFFF0000u);
  r.u[3] = (b.z & 0xFFFFu) | (b.w << 16);
  i.u[3] = (b.z >> 16)     | (b.w & 0xFFFF0000u);
  re = r.v; im = i.v;
}

// ---- cast params: B,C,D -> bf16 (Cim negated); A -> transposed [k][n] fp32
__global__ __launch_bounds__(256) void k_params(
    const float* Are, const float* Aim, const float* Bre, const float* Bim,
    const float* Cre, const float* Cim, const float* D,
    unsigned short* bre, unsigned short* bim, unsigned short* cre,
    unsigned short* cimn, unsigned short* dbf, float* atre, float* atim) {
  int idx = blockIdx.x * 256 + threadIdx.x;
  int stride = gridDim.x * 256;
  for (int i = idx; i < N * U; i += stride) { bre[i] = f2bf(Bre[i]); bim[i] = f2bf(Bim[i]); }
  for (int i = idx; i < P * N; i += stride) { cre[i] = f2bf(Cre[i]); cimn[i] = f2bf(-Cim[i]); }
  for (int i = idx; i < P * U; i += stride) { dbf[i] = f2bf(D[i]); }
  for (int i = idx; i < NK; i += stride) {
    int k = i >> 8, n = i & 255;
    atre[i] = Are[n * K + k];
    atim[i] = Aim[n * K + k];
  }
}

// ---- x (T,U,K) fp32 -> xT (T,K,U) bf16 (u contiguous), via LDS transpose
__global__ __launch_bounds__(256) void k_castx(const float* x, unsigned* xTu) {
  __shared__ float lds[U * 33];            // rows u, padded stride 33
  int t = blockIdx.x, tid = threadIdx.x;
  const float* xt = x + (size_t)t * (U * K);
#pragma unroll
  for (int it = 0; it < 16; it++) {
    int idx = it * 256 + tid;
    int u = idx >> 5, k = idx & 31;
    lds[u * 33 + k] = xt[idx];
  }
  __syncthreads();
  unsigned* dst = xTu + (size_t)t * (K * U / 2);
#pragma unroll
  for (int it = 0; it < 8; it++) {
    int k = it * 4 + (tid >> 6);
    int up = tid & 63;
    float f0 = lds[(2 * up) * 33 + k];
    float f1 = lds[(2 * up + 1) * 33 + k];
    dst[k * 64 + up] = (unsigned)f2bf(f0) | ((unsigned)f2bf(f1) << 16);
  }
}

// ---- zbuf[tl][k][n] (packed bf16 re|im) = B @ x_t, bf16 MFMA, M=k N=n Kd=u
__global__ __launch_bounds__(256) void k_bgemm(const unsigned short* xT,
                                               const unsigned short* bre,
                                               const unsigned short* bim,
                                               unsigned* zbuf, int t0) {
  int tl = blockIdx.x, tid = threadIdx.x;
  int w = tid >> 6, l = tid & 63, lq = l >> 4, lr = l & 15;
  const unsigned short* xrow = xT + (size_t)(t0 + tl) * (K * U);
  f32x4 accre[2][4], accim[2][4];
#pragma unroll
  for (int a = 0; a < 2; a++)
#pragma unroll
    for (int b = 0; b < 4; b++) { accre[a][b] = (f32x4)0.f; accim[a][b] = (f32x4)0.f; }
#pragma unroll
  for (int s = 0; s < 4; s++) {
    short8 afrag[2];
    afrag[0] = ld8(xrow + lr * U + s * 32 + lq * 8);
    afrag[1] = ld8(xrow + (16 + lr) * U + s * 32 + lq * 8);
#pragma unroll
    for (int nt = 0; nt < 4; nt++) {
      int n0 = (w * 4 + nt) * 16;
      short8 bfre = ld8(bre + (n0 + lr) * U + s * 32 + lq * 8);
      short8 bfim = ld8(bim + (n0 + lr) * U + s * 32 + lq * 8);
#pragma unroll
      for (int mt = 0; mt < 2; mt++) {
        accre[mt][nt] = __builtin_amdgcn_mfma_f32_16x16x32_bf16(afrag[mt], bfre, accre[mt][nt], 0, 0, 0);
        accim[mt][nt] = __builtin_amdgcn_mfma_f32_16x16x32_bf16(afrag[mt], bfim, accim[mt][nt], 0, 0, 0);
      }
    }
  }
  unsigned* dst = zbuf + (size_t)tl * NK;
#pragma unroll
  for (int mt = 0; mt < 2; mt++)
#pragma unroll
    for (int nt = 0; nt < 4; nt++) {
      int n0 = (w * 4 + nt) * 16;
#pragma unroll
      for (int r = 0; r < 4; r++) {
        int krow = mt * 16 + lq * 4 + r;
        dst[krow * 256 + n0 + lr] =
            (unsigned)f2bf(accre[mt][nt][r]) | ((unsigned)f2bf(accim[mt][nt][r]) << 16);
      }
    }
}

// ---- pass A: chunk-local scan, keep only chunk-end value
__global__ __launch_bounds__(256) void k_scanA(const unsigned* zbuf, const float* atre,
                                               const float* atim, float2* cend, int c0) {
  int bid = blockIdx.x;
  int cl = bid >> 5;                       // local chunk index within stage
  int lane = (bid & 31) * 256 + threadIdx.x;
  float ar = atre[lane], ai = atim[lane];
  float sr = 0.f, si = 0.f;
  const unsigned* src = zbuf + (size_t)cl * CL * NK + lane;
#pragma unroll 4
  for (int i = 0; i < CL; i++) {
    unsigned v = src[(size_t)i * NK];
    float ur = bf2f((unsigned short)(v & 0xFFFFu));
    float ui = bf2f((unsigned short)(v >> 16));
    float nr = ar * sr - ai * si + ur;
    float ni = ar * si + ai * sr + ui;
    sr = nr; si = ni;
  }
  cend[(size_t)(c0 + cl) * NK + lane] = make_float2(sr, si);
}

// ---- pass B: cross-chunk scan with multiplier a^CL; in-place cend -> carry
__global__ __launch_bounds__(256) void k_scanB(float2* cend, const float* atre,
                                               const float* atim) {
  int lane = blockIdx.x * 256 + threadIdx.x;
  float pr = atre[lane], pi = atim[lane];
#pragma unroll
  for (int i = 0; i < 6; i++) { float nr = pr * pr - pi * pi, ni = 2.f * pr * pi; pr = nr; pi = ni; }
  float cr = 0.f, ci = 0.f;
  for (int c = 0; c < NCH; c++) {
    float2 le = cend[(size_t)c * NK + lane];
    cend[(size_t)c * NK + lane] = make_float2(cr, ci);   // overwrite with carry-in
    float nr = pr * cr - pi * ci + le.x;
    float ni = pr * ci + pi * cr + le.y;
    cr = nr; ci = ni;
  }
}

// ---- pass C: replay with carry, overwrite zbuf in place with packed states
__global__ __launch_bounds__(256) void k_scanC(unsigned* zbuf, const float* atre,
                                               const float* atim, const float2* cend, int c0) {
  int bid = blockIdx.x;
  int cl = bid >> 5;
  int lane = (bid & 31) * 256 + threadIdx.x;
  float ar = atre[lane], ai = atim[lane];
  float2 cin = cend[(size_t)(c0 + cl) * NK + lane];
  float sr = cin.x, si = cin.y;
  unsigned* p = zbuf + (size_t)cl * CL * NK + lane;
#pragma unroll 4
  for (int i = 0; i < CL; i++) {
    unsigned v = p[(size_t)i * NK];
    float ur = bf2f((unsigned short)(v & 0xFFFFu));
    float ui = bf2f((unsigned short)(v >> 16));
    float nr = ar * sr - ai * si + ur;
    float ni = ar * si + ai * sr + ui;
    sr = nr; si = ni;
    p[(size_t)i * NK] = (unsigned)f2bf(sr) | ((unsigned)f2bf(si) << 16);
  }
}

// ---- out[t][p][k] = Cre@sre + (-Cim)@sim + D@x_t  (M=p, N=k, Kd=n then u)
__global__ __launch_bounds__(256) void k_out(const unsigned* zbuf,
                                             const unsigned short* cre, const unsigned short* cimn,
                                             const unsigned short* dbf, const unsigned short* xT,
                                             float* out, int t0) {
  int tl = blockIdx.x, tid = threadIdx.x;
  int t = t0 + tl;
  int w = tid >> 6, l = tid & 63, lq = l >> 4, lr = l & 15;
  f32x4 acc[2][2];
#pragma unroll
  for (int i = 0; i < 2; i++)
#pragma unroll
    for (int j = 0; j < 2; j++) acc[i][j] = (f32x4)0.f;
  const unsigned* zt = zbuf + (size_t)tl * NK;
#pragma unroll
  for (int s = 0; s < 8; s++) {
    int n0 = s * 32;
    short8 cfr[2], cfi[2], bfr[2], bfi[2];
#pragma unroll
    for (int i = 0; i < 2; i++) {
      int p = (w * 2 + i) * 16 + lr;
      cfr[i] = ld8(cre + p * N + n0 + lq * 8);
      cfi[i] = ld8(cimn + p * N + n0 + lq * 8);
    }
#pragma unroll
    for (int kt = 0; kt < 2; kt++) {
      int k = kt * 16 + lr;
      unpack8(zt + k * 256 + n0 + lq * 8, bfr[kt], bfi[kt]);
    }
#pragma unroll
    for (int i = 0; i < 2; i++)
#pragma unroll
      for (int kt = 0; kt < 2; kt++) {
        acc[i][kt] = __builtin_amdgcn_mfma_f32_16x16x32_bf16(cfr[i], bfr[kt], acc[i][kt], 0, 0, 0);
        acc[i][kt] = __builtin_amdgcn_mfma_f32_16x16x32_bf16(cfi[i], bfi[kt], acc[i][kt], 0, 0, 0);
      }
  }
  const unsigned short* xt = xT + (size_t)t * (K * U);
#pragma unroll
  for (int s = 0; s < 4; s++) {
    int u0 = s * 32;
    short8 dfr[2], xfr[2];
#pragma unroll
    for (int i = 0; i < 2; i++) {
      int p = (w * 2 + i) * 16 + lr;
      dfr[i] = ld8(dbf + p * U + u0 + lq * 8);
    }
#pragma unroll
    for (int kt = 0; kt < 2; kt++) {
      int k = kt * 16 + lr;
      xfr[kt] = ld8(xt + k * U + u0 + lq * 8);
    }
#pragma unroll
    for (int i = 0; i < 2; i++)
#pragma unroll
      for (int kt = 0; kt < 2; kt++)
        acc[i][kt] = __builtin_amdgcn_mfma_f32_16x16x32_bf16(dfr[i], xfr[kt], acc[i][kt], 0, 0, 0);
  }
  float* ot = out + (size_t)t * (P * K);
#pragma unroll
  for (int i = 0; i < 2; i++)
#pragma unroll
    for (int kt = 0; kt < 2; kt++)
#pragma unroll
      for (int r = 0; r < 4; r++) {
        int p = (w * 2 + i) * 16 + lq * 4 + r;
        int k = kt * 16 + lr;
        ot[p * K + k] = acc[i][kt][r];
      }
}

}  // namespace

extern "C" void kernel_launch(void* const* d_in, const int* in_sizes, int n_in,
                              void* d_out, int out_size, void* d_ws, size_t ws_size,
                              hipStream_t stream) {
  const float* x   = (const float*)d_in[0];
  const float* Are = (const float*)d_in[1];
  const float* Aim = (const float*)d_in[2];
  const float* Bre = (const float*)d_in[3];
  const float* Bim = (const float*)d_in[4];
  const float* Cre = (const float*)d_in[5];
  const float* Cim = (const float*)d_in[6];
  const float* D   = (const float*)d_in[7];
  float* out = (float*)d_out;

  auto al = [](size_t x_) { return (x_ + 255) & ~(size_t)255; };
  const size_t fixed = al((size_t)T * K * U * 2)      // xT
                     + al((size_t)NCH * NK * 8)       // cend
                     + 2 * al((size_t)N * U * 2)      // bre,bim
                     + 2 * al((size_t)P * N * 2)      // cre,cimn
                     + al((size_t)P * U * 2)          // dbf
                     + 2 * al((size_t)NK * 4);        // atre,atim
  // pick smallest stage count S whose zbuf fits; ws_size is constant -> graph-safe
  int S = 64;
  for (int s : {1, 2, 4, 8, 16, 32, 64}) {
    if (fixed + al((size_t)(T / s) * NK * 4) <= ws_size) { S = s; break; }
  }
  const int TS = T / S;        // timesteps per stage
  const int CS = NCH / S;      // chunks per stage

  char* w = (char*)d_ws;
  auto alloc = [&](size_t bytes) { void* p = (void*)w; w += (bytes + 255) & ~(size_t)255; return p; };
  unsigned* zbuf       = (unsigned*)alloc((size_t)TS * NK * 4);
  unsigned* xTu        = (unsigned*)alloc((size_t)T * K * U * 2);
  float2* cend         = (float2*)alloc((size_t)NCH * NK * 8);
  unsigned short* bre  = (unsigned short*)alloc((size_t)N * U * 2);
  unsigned short* bim  = (unsigned short*)alloc((size_t)N * U * 2);
  unsigned short* cre  = (unsigned short*)alloc((size_t)P * N * 2);
  unsigned short* cimn = (unsigned short*)alloc((size_t)P * N * 2);
  unsigned short* dbf  = (unsigned short*)alloc((size_t)P * U * 2);
  float* atre          = (float*)alloc((size_t)NK * 4);
  float* atim          = (float*)alloc((size_t)NK * 4);

  k_params<<<64, 256, 0, stream>>>(Are, Aim, Bre, Bim, Cre, Cim, D,
                                   bre, bim, cre, cimn, dbf, atre, atim);
  k_castx<<<T, 256, 0, stream>>>(x, xTu);

  const unsigned short* xT16 = (const unsigned short*)xTu;
  // pass 1: chunk-local ends
  for (int q = 0; q < S; q++) {
    k_bgemm<<<TS, 256, 0, stream>>>(xT16, bre, bim, zbuf, q * TS);
    k_scanA<<<CS * 32, 256, 0, stream>>>(zbuf, atre, atim, cend, q * CS);
  }
  // cross-chunk carries (in-place)
  k_scanB<<<NK / 256, 256, 0, stream>>>(cend, atre, atim);
  // pass 2: replay + output
  for (int q = 0; q < S; q++) {
    if (S > 1)  // zbuf was overwritten by later stages; recompute
      k_bgemm<<<TS, 256, 0, stream>>>(xT16, bre, bim, zbuf, q * TS);
    k_scanC<<<CS * 32, 256, 0, stream>>>(zbuf, atre, atim, cend, q * CS);
    k_out<<<TS, 256, 0, stream>>>(zbuf, cre, cimn, dbf, xT16, out, q * TS);
  }
}

// Round 3
// 357.577 us; speedup vs baseline: 1.2822x; 1.2822x over previous
//
#include <hip/hip_runtime.h>
#include <hip/hip_bf16.h>

namespace {

constexpr int T = 4096, N = 256, U = 128, K = 32, P = 128;
constexpr int NK = N * K;           // 8192 scan lanes
constexpr int CL = 64;              // chunk length
constexpr int NCH = T / CL;         // 64 chunks total
constexpr int TB = 8;               // timesteps per block in GEMM kernels

typedef __attribute__((ext_vector_type(8))) short short8;   // 8 bf16
typedef __attribute__((ext_vector_type(4))) float f32x4;

__device__ __forceinline__ unsigned short f2bf(float f) {
  union { float f; unsigned u; } v; v.f = f;
  unsigned r = v.u + 0x7FFFu + ((v.u >> 16) & 1u);   // RNE
  return (unsigned short)(r >> 16);
}
__device__ __forceinline__ float bf2f(unsigned short s) {
  union { unsigned u; float f; } v; v.u = ((unsigned)s) << 16;
  return v.f;
}
__device__ __forceinline__ short8 ld8(const unsigned short* p) {
  return *reinterpret_cast<const short8*>(p);
}
// 8 packed (re|im) dwords -> separate re/im bf16x8 fragments
__device__ __forceinline__ void unpack8(const unsigned* p, short8& re, short8& im) {
  uint4 a = *reinterpret_cast<const uint4*>(p);
  uint4 b = *reinterpret_cast<const uint4*>(p + 4);
  union { short8 v; unsigned u[4]; } r, i;
  r.u[0] = (a.x & 0xFFFFu) | (a.y << 16);
  i.u[0] = (a.x >> 16)     | (a.y & 0xFFFF0000u);
  r.u[1] = (a.z & 0xFFFFu) | (a.w << 16);
  i.u[1] = (a.z >> 16)     | (a.w & 0xFFFF0000u);
  r.u[2] = (b.x & 0xFFFFu) | (b.y << 16);
  i.u[2] = (b.x >> 16)     | (b.y & 0xFFFF0000u);
  r.u[3] = (b.z & 0xFFFFu) | (b.w << 16);
  i.u[3] = (b.z >> 16)     | (b.w & 0xFFFF0000u);
  re = r.v; im = i.v;
}

// ---- cast params: B,C,D -> bf16 (Cim negated); A -> transposed [k][n] fp32
__global__ __launch_bounds__(256) void k_params(
    const float* Are, const float* Aim, const float* Bre, const float* Bim,
    const float* Cre, const float* Cim, const float* D,
    unsigned short* bre, unsigned short* bim, unsigned short* cre,
    unsigned short* cimn, unsigned short* dbf, float* atre, float* atim) {
  int idx = blockIdx.x * 256 + threadIdx.x;
  int stride = gridDim.x * 256;
  for (int i = idx; i < N * U; i += stride) { bre[i] = f2bf(Bre[i]); bim[i] = f2bf(Bim[i]); }
  for (int i = idx; i < P * N; i += stride) { cre[i] = f2bf(Cre[i]); cimn[i] = f2bf(-Cim[i]); }
  for (int i = idx; i < P * U; i += stride) { dbf[i] = f2bf(D[i]); }
  for (int i = idx; i < NK; i += stride) {
    int k = i >> 8, n = i & 255;
    atre[i] = Are[n * K + k];
    atim[i] = Aim[n * K + k];
  }
}

// ---- x (T,U,K) fp32 -> xT (T,K,U) bf16 (u contiguous), via LDS transpose
__global__ __launch_bounds__(256) void k_castx(const float* x, unsigned* xTu) {
  __shared__ float lds[U * 33];            // rows u, padded stride 33
  int t = blockIdx.x, tid = threadIdx.x;
  const float* xt = x + (size_t)t * (U * K);
#pragma unroll
  for (int it = 0; it < 16; it++) {
    int idx = it * 256 + tid;
    int u = idx >> 5, k = idx & 31;
    lds[u * 33 + k] = xt[idx];
  }
  __syncthreads();
  unsigned* dst = xTu + (size_t)t * (K * U / 2);
#pragma unroll
  for (int it = 0; it < 8; it++) {
    int k = it * 4 + (tid >> 6);
    int up = tid & 63;
    float f0 = lds[(2 * up) * 33 + k];
    float f1 = lds[(2 * up + 1) * 33 + k];
    dst[k * 64 + up] = (unsigned)f2bf(f0) | ((unsigned)f2bf(f1) << 16);
  }
}

// ---- zbuf[tl][k][n] (packed bf16 re|im) = B @ x_t.  TB timesteps per block,
//      B fragments hoisted to registers (loaded once, reused TB times).
__global__ __launch_bounds__(256, 2) void k_bgemm(const unsigned short* xT,
                                                  const unsigned short* bre,
                                                  const unsigned short* bim,
                                                  unsigned* zbuf, int t0) {
  int blk = blockIdx.x, tid = threadIdx.x;
  int w = tid >> 6, l = tid & 63, lq = l >> 4, lr = l & 15;
  // hoist B fragments: wave w owns n-tiles (w*4+nt)*16
  short8 Bf_re[4][4], Bf_im[4][4];   // [s][nt] -> 128 VGPRs
#pragma unroll
  for (int s = 0; s < 4; s++)
#pragma unroll
    for (int nt = 0; nt < 4; nt++) {
      int n0 = (w * 4 + nt) * 16;
      Bf_re[s][nt] = ld8(bre + (n0 + lr) * U + s * 32 + lq * 8);
      Bf_im[s][nt] = ld8(bim + (n0 + lr) * U + s * 32 + lq * 8);
    }
  for (int tl = 0; tl < TB; tl++) {
    int tloc = blk * TB + tl;
    const unsigned short* xrow = xT + (size_t)(t0 + tloc) * (K * U);
    f32x4 accre[2][4], accim[2][4];
#pragma unroll
    for (int a = 0; a < 2; a++)
#pragma unroll
      for (int b = 0; b < 4; b++) { accre[a][b] = (f32x4)0.f; accim[a][b] = (f32x4)0.f; }
#pragma unroll
    for (int s = 0; s < 4; s++) {
      short8 afrag[2];
      afrag[0] = ld8(xrow + lr * U + s * 32 + lq * 8);
      afrag[1] = ld8(xrow + (16 + lr) * U + s * 32 + lq * 8);
#pragma unroll
      for (int nt = 0; nt < 4; nt++)
#pragma unroll
        for (int mt = 0; mt < 2; mt++) {
          accre[mt][nt] = __builtin_amdgcn_mfma_f32_16x16x32_bf16(afrag[mt], Bf_re[s][nt], accre[mt][nt], 0, 0, 0);
          accim[mt][nt] = __builtin_amdgcn_mfma_f32_16x16x32_bf16(afrag[mt], Bf_im[s][nt], accim[mt][nt], 0, 0, 0);
        }
    }
    unsigned* dst = zbuf + (size_t)tloc * NK;
#pragma unroll
    for (int mt = 0; mt < 2; mt++)
#pragma unroll
      for (int nt = 0; nt < 4; nt++) {
        int n0 = (w * 4 + nt) * 16;
#pragma unroll
        for (int r = 0; r < 4; r++) {
          int krow = mt * 16 + lq * 4 + r;
          dst[krow * 256 + n0 + lr] =
              (unsigned)f2bf(accre[mt][nt][r]) | ((unsigned)f2bf(accim[mt][nt][r]) << 16);
        }
      }
  }
}

// ---- pass A: chunk-local scan, keep only chunk-end value
__global__ __launch_bounds__(256) void k_scanA(const unsigned* zbuf, const float* atre,
                                               const float* atim, float2* cend, int c0) {
  int bid = blockIdx.x;
  int cl = bid >> 5;                       // local chunk index within stage
  int lane = (bid & 31) * 256 + threadIdx.x;
  float ar = atre[lane], ai = atim[lane];
  float sr = 0.f, si = 0.f;
  const unsigned* src = zbuf + (size_t)cl * CL * NK + lane;
#pragma unroll 4
  for (int i = 0; i < CL; i++) {
    unsigned v = src[(size_t)i * NK];
    float ur = bf2f((unsigned short)(v & 0xFFFFu));
    float ui = bf2f((unsigned short)(v >> 16));
    float nr = ar * sr - ai * si + ur;
    float ni = ar * si + ai * sr + ui;
    sr = nr; si = ni;
  }
  cend[(size_t)(c0 + cl) * NK + lane] = make_float2(sr, si);
}

// ---- pass B: cross-chunk scan with multiplier a^CL; in-place cend -> carry.
//      Batched 8-deep prefetch to avoid a 64-long serial HBM latency chain.
__global__ __launch_bounds__(256) void k_scanB(float2* cend, const float* atre,
                                               const float* atim) {
  int lane = blockIdx.x * 256 + threadIdx.x;
  float pr = atre[lane], pi = atim[lane];
#pragma unroll
  for (int i = 0; i < 6; i++) { float nr = pr * pr - pi * pi, ni = 2.f * pr * pi; pr = nr; pi = ni; }
  float cr = 0.f, ci = 0.f;
  for (int g = 0; g < NCH / 8; g++) {
    float2 buf[8];
#pragma unroll
    for (int j = 0; j < 8; j++) buf[j] = cend[(size_t)(g * 8 + j) * NK + lane];
#pragma unroll
    for (int j = 0; j < 8; j++) {
      cend[(size_t)(g * 8 + j) * NK + lane] = make_float2(cr, ci);   // carry-in
      float nr = pr * cr - pi * ci + buf[j].x;
      float ni = pr * ci + pi * cr + buf[j].y;
      cr = nr; ci = ni;
    }
  }
}

// ---- pass C: replay with carry, overwrite zbuf in place with packed states
__global__ __launch_bounds__(256) void k_scanC(unsigned* zbuf, const float* atre,
                                               const float* atim, const float2* cend, int c0) {
  int bid = blockIdx.x;
  int cl = bid >> 5;
  int lane = (bid & 31) * 256 + threadIdx.x;
  float ar = atre[lane], ai = atim[lane];
  float2 cin = cend[(size_t)(c0 + cl) * NK + lane];
  float sr = cin.x, si = cin.y;
  unsigned* p = zbuf + (size_t)cl * CL * NK + lane;
#pragma unroll 4
  for (int i = 0; i < CL; i++) {
    unsigned v = p[(size_t)i * NK];
    float ur = bf2f((unsigned short)(v & 0xFFFFu));
    float ui = bf2f((unsigned short)(v >> 16));
    float nr = ar * sr - ai * si + ur;
    float ni = ar * si + ai * sr + ui;
    sr = nr; si = ni;
    p[(size_t)i * NK] = (unsigned)f2bf(sr) | ((unsigned)f2bf(si) << 16);
  }
}

// ---- out[t][p][k] = Cre@sre + (-Cim)@sim + D@x_t.  TB timesteps per block,
//      C/D fragments hoisted to registers (loaded once, reused TB times).
__global__ __launch_bounds__(256, 2) void k_out(const unsigned* zbuf,
                                                const unsigned short* cre, const unsigned short* cimn,
                                                const unsigned short* dbf, const unsigned short* xT,
                                                float* out, int t0) {
  int blk = blockIdx.x, tid = threadIdx.x;
  int w = tid >> 6, l = tid & 63, lq = l >> 4, lr = l & 15;
  // hoist C fragments: wave w owns p-tiles (w*2+i)*16
  short8 Cf_re[8][2], Cf_im[8][2];   // [s][i] -> 128 VGPRs
#pragma unroll
  for (int s = 0; s < 8; s++)
#pragma unroll
    for (int i = 0; i < 2; i++) {
      int p = (w * 2 + i) * 16 + lr;
      Cf_re[s][i] = ld8(cre  + p * N + s * 32 + lq * 8);
      Cf_im[s][i] = ld8(cimn + p * N + s * 32 + lq * 8);
    }
  short8 Df[4][2];                    // [s][i] -> 32 VGPRs
#pragma unroll
  for (int s = 0; s < 4; s++)
#pragma unroll
    for (int i = 0; i < 2; i++) {
      int p = (w * 2 + i) * 16 + lr;
      Df[s][i] = ld8(dbf + p * U + s * 32 + lq * 8);
    }
  for (int tl = 0; tl < TB; tl++) {
    int tloc = blk * TB + tl;
    int t = t0 + tloc;
    f32x4 acc[2][2];
#pragma unroll
    for (int i = 0; i < 2; i++)
#pragma unroll
      for (int j = 0; j < 2; j++) acc[i][j] = (f32x4)0.f;
    const unsigned* zt = zbuf + (size_t)tloc * NK;
#pragma unroll
    for (int s = 0; s < 8; s++) {
      int n0 = s * 32;
      short8 bfr[2], bfi[2];
#pragma unroll
      for (int kt = 0; kt < 2; kt++) {
        int k = kt * 16 + lr;
        unpack8(zt + k * 256 + n0 + lq * 8, bfr[kt], bfi[kt]);
      }
#pragma unroll
      for (int i = 0; i < 2; i++)
#pragma unroll
        for (int kt = 0; kt < 2; kt++) {
          acc[i][kt] = __builtin_amdgcn_mfma_f32_16x16x32_bf16(Cf_re[s][i], bfr[kt], acc[i][kt], 0, 0, 0);
          acc[i][kt] = __builtin_amdgcn_mfma_f32_16x16x32_bf16(Cf_im[s][i], bfi[kt], acc[i][kt], 0, 0, 0);
        }
    }
    const unsigned short* xt = xT + (size_t)t * (K * U);
#pragma unroll
    for (int s = 0; s < 4; s++) {
      int u0 = s * 32;
      short8 xfr[2];
#pragma unroll
      for (int kt = 0; kt < 2; kt++) {
        int k = kt * 16 + lr;
        xfr[kt] = ld8(xt + k * U + u0 + lq * 8);
      }
#pragma unroll
      for (int i = 0; i < 2; i++)
#pragma unroll
        for (int kt = 0; kt < 2; kt++)
          acc[i][kt] = __builtin_amdgcn_mfma_f32_16x16x32_bf16(Df[s][i], xfr[kt], acc[i][kt], 0, 0, 0);
    }
    float* ot = out + (size_t)t * (P * K);
#pragma unroll
    for (int i = 0; i < 2; i++)
#pragma unroll
      for (int kt = 0; kt < 2; kt++)
#pragma unroll
        for (int r = 0; r < 4; r++) {
          int p = (w * 2 + i) * 16 + lq * 4 + r;
          int k = kt * 16 + lr;
          ot[p * K + k] = acc[i][kt][r];
        }
  }
}

}  // namespace

extern "C" void kernel_launch(void* const* d_in, const int* in_sizes, int n_in,
                              void* d_out, int out_size, void* d_ws, size_t ws_size,
                              hipStream_t stream) {
  const float* x   = (const float*)d_in[0];
  const float* Are = (const float*)d_in[1];
  const float* Aim = (const float*)d_in[2];
  const float* Bre = (const float*)d_in[3];
  const float* Bim = (const float*)d_in[4];
  const float* Cre = (const float*)d_in[5];
  const float* Cim = (const float*)d_in[6];
  const float* D   = (const float*)d_in[7];
  float* out = (float*)d_out;

  auto al = [](size_t x_) { return (x_ + 255) & ~(size_t)255; };
  const size_t fixed = al((size_t)T * K * U * 2)      // xT
                     + al((size_t)NCH * NK * 8)       // cend
                     + 2 * al((size_t)N * U * 2)      // bre,bim
                     + 2 * al((size_t)P * N * 2)      // cre,cimn
                     + al((size_t)P * U * 2)          // dbf
                     + 2 * al((size_t)NK * 4);        // atre,atim
  // pick smallest stage count S whose zbuf fits; ws_size is constant -> graph-safe
  int S = 64;
  for (int s : {1, 2, 4, 8, 16, 32, 64}) {
    if (fixed + al((size_t)(T / s) * NK * 4) <= ws_size) { S = s; break; }
  }
  const int TS = T / S;        // timesteps per stage
  const int CS = NCH / S;      // chunks per stage

  char* w = (char*)d_ws;
  auto alloc = [&](size_t bytes) { void* p = (void*)w; w += (bytes + 255) & ~(size_t)255; return p; };
  unsigned* zbuf       = (unsigned*)alloc((size_t)TS * NK * 4);
  unsigned* xTu        = (unsigned*)alloc((size_t)T * K * U * 2);
  float2* cend         = (float2*)alloc((size_t)NCH * NK * 8);
  unsigned short* bre  = (unsigned short*)alloc((size_t)N * U * 2);
  unsigned short* bim  = (unsigned short*)alloc((size_t)N * U * 2);
  unsigned short* cre  = (unsigned short*)alloc((size_t)P * N * 2);
  unsigned short* cimn = (unsigned short*)alloc((size_t)P * N * 2);
  unsigned short* dbf  = (unsigned short*)alloc((size_t)P * U * 2);
  float* atre          = (float*)alloc((size_t)NK * 4);
  float* atim          = (float*)alloc((size_t)NK * 4);

  k_params<<<64, 256, 0, stream>>>(Are, Aim, Bre, Bim, Cre, Cim, D,
                                   bre, bim, cre, cimn, dbf, atre, atim);
  k_castx<<<T, 256, 0, stream>>>(x, xTu);

  const unsigned short* xT16 = (const unsigned short*)xTu;
  // pass 1: chunk-local ends
  for (int q = 0; q < S; q++) {
    k_bgemm<<<TS / TB, 256, 0, stream>>>(xT16, bre, bim, zbuf, q * TS);
    k_scanA<<<CS * 32, 256, 0, stream>>>(zbuf, atre, atim, cend, q * CS);
  }
  // cross-chunk carries (in-place)
  k_scanB<<<NK / 256, 256, 0, stream>>>(cend, atre, atim);
  // pass 2: replay + output
  for (int q = 0; q < S; q++) {
    if (S > 1)  // zbuf was overwritten by later stages; recompute
      k_bgemm<<<TS / TB, 256, 0, stream>>>(xT16, bre, bim, zbuf, q * TS);
    k_scanC<<<CS * 32, 256, 0, stream>>>(zbuf, atre, atim, cend, q * CS);
    k_out<<<TS / TB, 256, 0, stream>>>(zbuf, cre, cimn, dbf, xT16, out, q * TS);
  }
}

// Round 4
// 311.838 us; speedup vs baseline: 1.4702x; 1.1467x over previous
//
#include <hip/hip_runtime.h>
#include <hip/hip_bf16.h>

namespace {

constexpr int T = 4096, N = 256, U = 128, K = 32, P = 128;
constexpr int NK = N * K;           // 8192 scan lanes
constexpr int CL = 64;              // chunk length
constexpr int NCH = T / CL;         // 64 chunks total
constexpr int TB = 8;               // timesteps per block in GEMM kernels

typedef __attribute__((ext_vector_type(8))) short short8;   // 8 bf16
typedef __attribute__((ext_vector_type(4))) float f32x4;
typedef __attribute__((address_space(3))) unsigned lds_u32;
typedef __attribute__((address_space(1))) const unsigned glb_u32;

__device__ __forceinline__ unsigned short f2bf(float f) {
  union { float f; unsigned u; } v; v.f = f;
  unsigned r = v.u + 0x7FFFu + ((v.u >> 16) & 1u);   // RNE
  return (unsigned short)(r >> 16);
}
__device__ __forceinline__ float bf2f(unsigned short s) {
  union { unsigned u; float f; } v; v.u = ((unsigned)s) << 16;
  return v.f;
}
__device__ __forceinline__ short8 ld8(const unsigned short* p) {
  return *reinterpret_cast<const short8*>(p);
}
// async global->LDS, 16 B per lane; LDS dest = wave-uniform base + lane*16
__device__ __forceinline__ void dma16(const unsigned* g, unsigned* l) {
  __builtin_amdgcn_global_load_lds((glb_u32*)g, (lds_u32*)l, 16, 0, 0);
}

// Swizzled storage index (dwords) of logical element (k,n) within a t-slice.
// Breaks the 16-way LDS bank conflict of the plain [k][n] layout: start quads
// spread over all 8 bank-quads, 2 lanes each (free 2-way).
__device__ __forceinline__ int zswz(int k, int n) {
  int n8 = n >> 3, j = n & 7;
  return k * 256 + ((n8 ^ (k & 7)) << 3) + (j ^ (((k >> 3) & 1) << 2));
}

// a = dwords for n8*8+{0..3}, b = n8*8+{4..7}; each dword packs (re|im) bf16
__device__ __forceinline__ void unpackAB(uint4 a, uint4 b, short8& re, short8& im) {
  union { short8 v; unsigned u[4]; } r, i;
  r.u[0] = (a.x & 0xFFFFu) | (a.y << 16);
  i.u[0] = (a.x >> 16)     | (a.y & 0xFFFF0000u);
  r.u[1] = (a.z & 0xFFFFu) | (a.w << 16);
  i.u[1] = (a.z >> 16)     | (a.w & 0xFFFF0000u);
  r.u[2] = (b.x & 0xFFFFu) | (b.y << 16);
  i.u[2] = (b.x >> 16)     | (b.y & 0xFFFF0000u);
  r.u[3] = (b.z & 0xFFFFu) | (b.w << 16);
  i.u[3] = (b.z >> 16)     | (b.w & 0xFFFF0000u);
  re = r.v; im = i.v;
}

// ---- cast params: B,C,D -> bf16 (Cim negated); A -> swizzled-lane-order fp32
__global__ __launch_bounds__(256) void k_params(
    const float* Are, const float* Aim, const float* Bre, const float* Bim,
    const float* Cre, const float* Cim, const float* D,
    unsigned short* bre, unsigned short* bim, unsigned short* cre,
    unsigned short* cimn, unsigned short* dbf, float* atre, float* atim) {
  int idx = blockIdx.x * 256 + threadIdx.x;
  int stride = gridDim.x * 256;
  for (int i = idx; i < N * U; i += stride) { bre[i] = f2bf(Bre[i]); bim[i] = f2bf(Bim[i]); }
  for (int i = idx; i < P * N; i += stride) { cre[i] = f2bf(Cre[i]); cimn[i] = f2bf(-Cim[i]); }
  for (int i = idx; i < P * U; i += stride) { dbf[i] = f2bf(D[i]); }
  for (int i = idx; i < NK; i += stride) {
    // i is the STORAGE index; invert zswz (XOR is involutive)
    int k = i >> 8, r = i & 255;
    int n8 = (r >> 3) ^ (k & 7);
    int j  = (r & 7) ^ (((k >> 3) & 1) << 2);
    int n = n8 * 8 + j;
    atre[i] = Are[n * K + k];
    atim[i] = Aim[n * K + k];
  }
}

// ---- x (T,U,K) fp32 -> xT (T,K,U) bf16 (u contiguous), via LDS transpose
__global__ __launch_bounds__(256) void k_castx(const float* x, unsigned* xTu) {
  __shared__ float lds[U * 33];            // rows u, padded stride 33
  int t = blockIdx.x, tid = threadIdx.x;
  const float* xt = x + (size_t)t * (U * K);
#pragma unroll
  for (int it = 0; it < 16; it++) {
    int idx = it * 256 + tid;
    int u = idx >> 5, k = idx & 31;
    lds[u * 33 + k] = xt[idx];
  }
  __syncthreads();
  unsigned* dst = xTu + (size_t)t * (K * U / 2);
#pragma unroll
  for (int it = 0; it < 8; it++) {
    int k = it * 4 + (tid >> 6);
    int up = tid & 63;
    float f0 = lds[(2 * up) * 33 + k];
    float f1 = lds[(2 * up + 1) * 33 + k];
    dst[k * 64 + up] = (unsigned)f2bf(f0) | ((unsigned)f2bf(f1) << 16);
  }
}

// ---- zbuf[tl][swz(k,n)] (packed bf16 re|im) = B @ x_t.  TB timesteps/block,
//      B fragments register-resident (waves_per_eu(2,2) -> 256-VGPR budget).
__global__ __launch_bounds__(256)
__attribute__((amdgpu_waves_per_eu(2, 2)))
void k_bgemm(const unsigned short* xT, const unsigned short* bre,
             const unsigned short* bim, unsigned* zbuf, int t0) {
  int blk = blockIdx.x, tid = threadIdx.x;
  int w = tid >> 6, l = tid & 63, lq = l >> 4, lr = l & 15;
  // hoist B fragments: wave w owns n-tiles (w*4+nt)*16
  short8 Bf_re[4][4], Bf_im[4][4];   // [s][nt] -> 128 VGPRs
#pragma unroll
  for (int s = 0; s < 4; s++)
#pragma unroll
    for (int nt = 0; nt < 4; nt++) {
      int n0 = (w * 4 + nt) * 16;
      Bf_re[s][nt] = ld8(bre + (n0 + lr) * U + s * 32 + lq * 8);
      Bf_im[s][nt] = ld8(bim + (n0 + lr) * U + s * 32 + lq * 8);
    }
#pragma unroll
  for (int tl = 0; tl < TB; tl++) {
    int tloc = blk * TB + tl;
    const unsigned short* xrow = xT + (size_t)(t0 + tloc) * (K * U);
    // all 8 A-fragment loads issued up front; MFMA stream covers latency
    short8 af[4][2];
#pragma unroll
    for (int s = 0; s < 4; s++) {
      af[s][0] = ld8(xrow + lr * U + s * 32 + lq * 8);
      af[s][1] = ld8(xrow + (16 + lr) * U + s * 32 + lq * 8);
    }
    f32x4 accre[2][4], accim[2][4];
#pragma unroll
    for (int a = 0; a < 2; a++)
#pragma unroll
      for (int b = 0; b < 4; b++) { accre[a][b] = (f32x4)0.f; accim[a][b] = (f32x4)0.f; }
#pragma unroll
    for (int s = 0; s < 4; s++)
#pragma unroll
      for (int nt = 0; nt < 4; nt++)
#pragma unroll
        for (int mt = 0; mt < 2; mt++) {
          accre[mt][nt] = __builtin_amdgcn_mfma_f32_16x16x32_bf16(af[s][mt], Bf_re[s][nt], accre[mt][nt], 0, 0, 0);
          accim[mt][nt] = __builtin_amdgcn_mfma_f32_16x16x32_bf16(af[s][mt], Bf_im[s][nt], accim[mt][nt], 0, 0, 0);
        }
    unsigned* dst = zbuf + (size_t)tloc * NK;
#pragma unroll
    for (int mt = 0; mt < 2; mt++)
#pragma unroll
      for (int nt = 0; nt < 4; nt++) {
        int n0 = (w * 4 + nt) * 16;
#pragma unroll
        for (int r = 0; r < 4; r++) {
          int krow = mt * 16 + lq * 4 + r;
          dst[zswz(krow, n0 + lr)] =
              (unsigned)f2bf(accre[mt][nt][r]) | ((unsigned)f2bf(accim[mt][nt][r]) << 16);
        }
      }
  }
}

// ---- pass A: chunk-local scan, keep only chunk-end value
__global__ __launch_bounds__(256) void k_scanA(const unsigned* zbuf, const float* atre,
                                               const float* atim, float2* cend, int c0) {
  int bid = blockIdx.x;
  int cl = bid >> 5;                       // local chunk index within stage
  int lane = (bid & 31) * 256 + threadIdx.x;
  float ar = atre[lane], ai = atim[lane];
  float sr = 0.f, si = 0.f;
  const unsigned* src = zbuf + (size_t)cl * CL * NK + lane;
#pragma unroll 8
  for (int i = 0; i < CL; i++) {
    unsigned v = src[(size_t)i * NK];
    float ur = bf2f((unsigned short)(v & 0xFFFFu));
    float ui = bf2f((unsigned short)(v >> 16));
    float nr = ar * sr - ai * si + ur;
    float ni = ar * si + ai * sr + ui;
    sr = nr; si = ni;
  }
  cend[(size_t)(c0 + cl) * NK + lane] = make_float2(sr, si);
}

// ---- pass B: cross-chunk scan with multiplier a^CL; in-place cend -> carry
__global__ __launch_bounds__(256) void k_scanB(float2* cend, const float* atre,
                                               const float* atim) {
  int lane = blockIdx.x * 256 + threadIdx.x;
  float pr = atre[lane], pi = atim[lane];
#pragma unroll
  for (int i = 0; i < 6; i++) { float nr = pr * pr - pi * pi, ni = 2.f * pr * pi; pr = nr; pi = ni; }
  float cr = 0.f, ci = 0.f;
  for (int g = 0; g < NCH / 8; g++) {
    float2 buf[8];
#pragma unroll
    for (int j = 0; j < 8; j++) buf[j] = cend[(size_t)(g * 8 + j) * NK + lane];
#pragma unroll
    for (int j = 0; j < 8; j++) {
      cend[(size_t)(g * 8 + j) * NK + lane] = make_float2(cr, ci);   // carry-in
      float nr = pr * cr - pi * ci + buf[j].x;
      float ni = pr * ci + pi * cr + buf[j].y;
      cr = nr; ci = ni;
    }
  }
}

// ---- pass C: replay with carry, overwrite zbuf in place with packed states
__global__ __launch_bounds__(256) void k_scanC(unsigned* zbuf, const float* atre,
                                               const float* atim, const float2* cend, int c0) {
  int bid = blockIdx.x;
  int cl = bid >> 5;
  int lane = (bid & 31) * 256 + threadIdx.x;
  float ar = atre[lane], ai = atim[lane];
  float2 cin = cend[(size_t)(c0 + cl) * NK + lane];
  float sr = cin.x, si = cin.y;
  unsigned* p = zbuf + (size_t)cl * CL * NK + lane;
#pragma unroll 8
  for (int i = 0; i < CL; i++) {
    unsigned v = p[(size_t)i * NK];
    float ur = bf2f((unsigned short)(v & 0xFFFFu));
    float ui = bf2f((unsigned short)(v >> 16));
    float nr = ar * sr - ai * si + ur;
    float ni = ar * si + ai * sr + ui;
    sr = nr; si = ni;
    p[(size_t)i * NK] = (unsigned)f2bf(sr) | ((unsigned)f2bf(si) << 16);
  }
}

// ---- out[t][p][k] = Cre@sre + (-Cim)@sim + D@x_t.  States staged to LDS via
//      async DMA (double-buffered, prefetch t+1 during compute of t); C/D
//      register-resident.  LDS layout = swizzled zbuf slice (conflict-free).
__global__ __launch_bounds__(256)
__attribute__((amdgpu_waves_per_eu(2, 2)))
void k_out(const unsigned* zbuf,
           const unsigned short* cre, const unsigned short* cimn,
           const unsigned short* dbf, const unsigned short* xT,
           float* out, int t0) {
  __shared__ unsigned ldsz[2][NK];   // 2 x 32 KB
  int blk = blockIdx.x, tid = threadIdx.x;
  int w = tid >> 6, l = tid & 63, lq = l >> 4, lr = l & 15;
  int h = (lr >> 3) & 1;             // == ((k>>3)&1) for k = kt*16+lr
  // hoist C fragments: wave w owns p-tiles (w*2+i)*16
  short8 Cf_re[8][2], Cf_im[8][2];   // 128 VGPRs
#pragma unroll
  for (int s = 0; s < 8; s++)
#pragma unroll
    for (int i = 0; i < 2; i++) {
      int p = (w * 2 + i) * 16 + lr;
      Cf_re[s][i] = ld8(cre  + p * N + s * 32 + lq * 8);
      Cf_im[s][i] = ld8(cimn + p * N + s * 32 + lq * 8);
    }
  short8 Df[4][2];                   // 32 VGPRs
#pragma unroll
  for (int s = 0; s < 4; s++)
#pragma unroll
    for (int i = 0; i < 2; i++) {
      int p = (w * 2 + i) * 16 + lr;
      Df[s][i] = ld8(dbf + p * U + s * 32 + lq * 8);
    }
  // initial DMA: t-slice 0 of this block (8192 dwords = 8 x 256 lanes x 16 B)
  {
    const unsigned* z0 = zbuf + (size_t)(blk * TB) * NK;
#pragma unroll
    for (int it = 0; it < 8; it++)
      dma16(z0 + it * 1024 + tid * 4, &ldsz[0][it * 1024 + tid * 4]);
  }
  __syncthreads();
  int cur = 0;
  for (int tl = 0; tl < TB; tl++) {
    int tloc = blk * TB + tl;
    int t = t0 + tloc;
    // async prefetch of next t-slice into the other buffer
    if (tl + 1 < TB) {
      const unsigned* zn = zbuf + (size_t)(tloc + 1) * NK;
#pragma unroll
      for (int it = 0; it < 8; it++)
        dma16(zn + it * 1024 + tid * 4, &ldsz[cur ^ 1][it * 1024 + tid * 4]);
    }
    // x fragments: plain global loads issued early; C-MFMA stream covers them
    const unsigned short* xt = xT + (size_t)t * (K * U);
    short8 xfr[4][2];
#pragma unroll
    for (int s = 0; s < 4; s++)
#pragma unroll
      for (int kt = 0; kt < 2; kt++)
        xfr[s][kt] = ld8(xt + (kt * 16 + lr) * U + s * 32 + lq * 8);
    f32x4 acc[2][2];
#pragma unroll
    for (int i = 0; i < 2; i++)
#pragma unroll
      for (int j = 0; j < 2; j++) acc[i][j] = (f32x4)0.f;
    const unsigned* zl = &ldsz[cur][0];
#pragma unroll
    for (int s = 0; s < 8; s++) {
      short8 bfr[2], bfi[2];
#pragma unroll
      for (int kt = 0; kt < 2; kt++) {
        int k = kt * 16 + lr;
        int n8 = s * 4 + lq;
        const uint4* q = reinterpret_cast<const uint4*>(zl + k * 256 + ((n8 ^ (k & 7)) << 3));
        uint4 a = q[h], b = q[h ^ 1];
        unpackAB(a, b, bfr[kt], bfi[kt]);
      }
#pragma unroll
      for (int i = 0; i < 2; i++)
#pragma unroll
        for (int kt = 0; kt < 2; kt++) {
          acc[i][kt] = __builtin_amdgcn_mfma_f32_16x16x32_bf16(Cf_re[s][i], bfr[kt], acc[i][kt], 0, 0, 0);
          acc[i][kt] = __builtin_amdgcn_mfma_f32_16x16x32_bf16(Cf_im[s][i], bfi[kt], acc[i][kt], 0, 0, 0);
        }
    }
#pragma unroll
    for (int s = 0; s < 4; s++)
#pragma unroll
      for (int i = 0; i < 2; i++)
#pragma unroll
        for (int kt = 0; kt < 2; kt++)
          acc[i][kt] = __builtin_amdgcn_mfma_f32_16x16x32_bf16(Df[s][i], xfr[s][kt], acc[i][kt], 0, 0, 0);
    float* ot = out + (size_t)t * (P * K);
#pragma unroll
    for (int i = 0; i < 2; i++)
#pragma unroll
      for (int kt = 0; kt < 2; kt++)
#pragma unroll
        for (int r = 0; r < 4; r++) {
          int p = (w * 2 + i) * 16 + lq * 4 + r;
          int k = kt * 16 + lr;
          ot[p * K + k] = acc[i][kt][r];
        }
    __syncthreads();   // drains prefetch DMA + protects buffer swap
    cur ^= 1;
  }
}

}  // namespace

extern "C" void kernel_launch(void* const* d_in, const int* in_sizes, int n_in,
                              void* d_out, int out_size, void* d_ws, size_t ws_size,
                              hipStream_t stream) {
  const float* x   = (const float*)d_in[0];
  const float* Are = (const float*)d_in[1];
  const float* Aim = (const float*)d_in[2];
  const float* Bre = (const float*)d_in[3];
  const float* Bim = (const float*)d_in[4];
  const float* Cre = (const float*)d_in[5];
  const float* Cim = (const float*)d_in[6];
  const float* D   = (const float*)d_in[7];
  float* out = (float*)d_out;

  auto al = [](size_t x_) { return (x_ + 255) & ~(size_t)255; };
  const size_t fixed = al((size_t)T * K * U * 2)      // xT
                     + al((size_t)NCH * NK * 8)       // cend
                     + 2 * al((size_t)N * U * 2)      // bre,bim
                     + 2 * al((size_t)P * N * 2)      // cre,cimn
                     + al((size_t)P * U * 2)          // dbf
                     + 2 * al((size_t)NK * 4);        // atre,atim
  int S = 64;
  for (int s : {1, 2, 4, 8, 16, 32, 64}) {
    if (fixed + al((size_t)(T / s) * NK * 4) <= ws_size) { S = s; break; }
  }
  const int TS = T / S;        // timesteps per stage
  const int CS = NCH / S;      // chunks per stage

  char* w = (char*)d_ws;
  auto alloc = [&](size_t bytes) { void* p = (void*)w; w += (bytes + 255) & ~(size_t)255; return p; };
  unsigned* zbuf       = (unsigned*)alloc((size_t)TS * NK * 4);
  unsigned* xTu        = (unsigned*)alloc((size_t)T * K * U * 2);
  float2* cend         = (float2*)alloc((size_t)NCH * NK * 8);
  unsigned short* bre  = (unsigned short*)alloc((size_t)N * U * 2);
  unsigned short* bim  = (unsigned short*)alloc((size_t)N * U * 2);
  unsigned short* cre  = (unsigned short*)alloc((size_t)P * N * 2);
  unsigned short* cimn = (unsigned short*)alloc((size_t)P * N * 2);
  unsigned short* dbf  = (unsigned short*)alloc((size_t)P * U * 2);
  float* atre          = (float*)alloc((size_t)NK * 4);
  float* atim          = (float*)alloc((size_t)NK * 4);

  k_params<<<64, 256, 0, stream>>>(Are, Aim, Bre, Bim, Cre, Cim, D,
                                   bre, bim, cre, cimn, dbf, atre, atim);
  k_castx<<<T, 256, 0, stream>>>(x, xTu);

  const unsigned short* xT16 = (const unsigned short*)xTu;
  // pass 1: chunk-local ends
  for (int q = 0; q < S; q++) {
    k_bgemm<<<TS / TB, 256, 0, stream>>>(xT16, bre, bim, zbuf, q * TS);
    k_scanA<<<CS * 32, 256, 0, stream>>>(zbuf, atre, atim, cend, q * CS);
  }
  // cross-chunk carries (in-place)
  k_scanB<<<NK / 256, 256, 0, stream>>>(cend, atre, atim);
  // pass 2: replay + output
  for (int q = 0; q < S; q++) {
    if (S > 1)  // zbuf was overwritten by later stages; recompute
      k_bgemm<<<TS / TB, 256, 0, stream>>>(xT16, bre, bim, zbuf, q * TS);
    k_scanC<<<CS * 32, 256, 0, stream>>>(zbuf, atre, atim, cend, q * CS);
    k_out<<<TS / TB, 256, 0, stream>>>(zbuf, cre, cimn, dbf, xT16, out, q * TS);
  }
}